// Round 2
// baseline (601.773 us; speedup 1.0000x reference)
//
#include <hip/hip_runtime.h>

#define EPSF 1e-8f
#define RCUT 4.8f
#define NB 64
#define NSEL 20

__device__ __forceinline__ float fast_tanh(float x) {
    float e = __expf(2.0f * x);
    return 1.0f - __fdividef(2.0f, e + 1.0f);
}

// ---------------- Kernel A: norms + select 20 nearest (sorted) ----------------
extern "C" __global__ void __launch_bounds__(256)
sel_kernel(const float* __restrict__ dr, const float* __restrict__ W0,
           float* __restrict__ ws_R, float* __restrict__ ws_fc,
           float* __restrict__ ws_F, int* __restrict__ ws_idx,
           float* __restrict__ ws_ndn, float* __restrict__ ws_W0T)
{
    __shared__ float R_s[256];
    const int t = threadIdx.x;
    const int g = t >> 6;       // which b within block (0..3)
    const int j = t & 63;       // neighbor id
    const int b = blockIdx.x * 4 + g;

    const float* p = dr + ((size_t)b * NB + j) * 3;
    float x = p[0] + EPSF, y = p[1] + EPSF, z = p[2] + EPSF;
    float R = sqrtf(x * x + y * y + z * z);
    R_s[t] = R;
    __syncthreads();

    // stable rank: count (Rk < R) or (Rk == R and k < j)
    int rank = 0;
    const float* grp = R_s + g * 64;
    #pragma unroll 8
    for (int k = 0; k < 64; ++k) {
        float Rk = grp[k];
        rank += (Rk < R || (Rk == R && k < j)) ? 1 : 0;
    }

    float fc = 0.0f;
    if (rank < NSEL) {
        fc = (R > RCUT) ? 0.0f
                        : (0.5f * __cosf(3.14159265358979323846f * R / RCUT) + 0.5f);
        size_t o = (size_t)b * NSEL + rank;
        ws_R[o]  = R;
        ws_fc[o] = fc;
        ws_idx[o] = j;
        float inv = 1.0f / R;
        ws_ndn[o * 3 + 0] = x * inv;
        ws_ndn[o * 3 + 1] = y * inv;
        ws_ndn[o * 3 + 2] = z * inv;
    }

    // F[b] = sum of selected fc over this wave (each group is exactly one wave)
    float F = fc;
    for (int off = 32; off > 0; off >>= 1) F += __shfl_xor(F, off, 64);
    if (j == 0) ws_F[b] = F;

    // one-time W0 transpose (block 0 only; A always runs before B on the stream)
    if (blockIdx.x == 0) {
        for (int i = t; i < 15 * 64; i += 256) {
            int k = i >> 6, jj = i & 63;
            ws_W0T[jj * 15 + k] = W0[i];
        }
    }
}

// ---------------- Kernel B: per-pair MLP fwd + analytic bwd ----------------
// (320,4): cap 128 total regs/wave (acc[64] in AGPRs + <=64 arch) so 3 blocks/CU
// co-reside. R5: weights (W1 16KB, W0T 3.75KB, b0/b1/W2) staged in LDS once per
// block -- the per-j-pair weight stream was s_load/L2-latency exposed (VALUBusy
// 47% at 4 waves/SIMD). Uniform-address ds_read broadcasts are ~64cy and overlap
// under the 256cy of FMA issue per pair. LDS total ~38.7KB -> 4 blocks/CU by
// LDS, still >= the 3-block register limit (occupancy unchanged; stall fix).
extern "C" __global__ void __launch_bounds__(320, 4)
energy_kernel(const float* __restrict__ orientation, const float* __restrict__ n_or,
              const float* __restrict__ W0T, const float* __restrict__ b0,
              const float* __restrict__ W1, const float* __restrict__ b1,
              const float* __restrict__ W2, const float* __restrict__ b2v,
              const float* __restrict__ f1, const float* __restrict__ f2,
              const float* __restrict__ ws_R, const float* __restrict__ ws_fc,
              const float* __restrict__ ws_F, const int* __restrict__ ws_idx,
              const float* __restrict__ ws_ndn,
              float* __restrict__ out_force, float* __restrict__ out_torque,
              float* __restrict__ out_energy)
{
    __shared__ float sW1[64 * 64];     // 16 KB   [j][i]
    __shared__ float sW0T[64 * 15];    // 3.75 KB [j][k]
    __shared__ float sB0[64];
    __shared__ float sB1[64];
    __shared__ float sW2[64];
    __shared__ float p_s[320];
    __shared__ float red[320][12];
    __shared__ float G[16][12];

    const int t = threadIdx.x;
    const int bl = t / 20;      // local b (0..15)
    const int n  = t % 20;      // selected-neighbor slot
    const int b  = blockIdx.x * 16 + bl;
    const size_t o = (size_t)b * NSEL + n;

    // ---- stage weights to LDS (issue loads first so they overlap feat calc) ----
    for (int i = t; i < 64 * 64; i += 320) sW1[i] = W1[i];
    for (int i = t; i < 64 * 15; i += 320) sW0T[i] = W0T[i];
    if (t < 64) { sB0[t] = b0[t]; sB1[t] = b1[t]; sW2[t] = W2[t]; }

    // feat = [dr_o(3), dr_no(3), o_no(9)]; O/Nr/nd scoped so they die here.
    float feat[15];
    {
        const float nd0 = ws_ndn[o * 3 + 0];
        const float nd1 = ws_ndn[o * 3 + 1];
        const float nd2 = ws_ndn[o * 3 + 2];
        const int  idx = ws_idx[o];
        float O[9], Nr[9];
        const float* Op = orientation + (size_t)b * 9;
        #pragma unroll
        for (int i = 0; i < 9; ++i) O[i] = Op[i];
        const float* Np = n_or + ((size_t)b * NB + idx) * 9;
        #pragma unroll
        for (int i = 0; i < 9; ++i) Nr[i] = Np[i];

        #pragma unroll
        for (int h = 0; h < 3; ++h)
            feat[h] = nd0 * O[h] + nd1 * O[3 + h] + nd2 * O[6 + h];
        #pragma unroll
        for (int h = 0; h < 3; ++h)
            feat[3 + h] = nd0 * Nr[h] + nd1 * Nr[3 + h] + nd2 * Nr[6 + h];
        #pragma unroll
        for (int l = 0; l < 3; ++l)
            #pragma unroll
            for (int m = 0; m < 3; ++m)
                feat[6 + l * 3 + m] = O[l] * Nr[m] + O[3 + l] * Nr[3 + m] + O[6 + l] * Nr[6 + m];
    }

    __syncthreads();   // weights staged

    // ---------- forward (j, j+1 interleaved for 2x ILP on the serial chain) ----
    float acc[64];                      // z2 accumulators -> h2 -> dz2 (in place)
    #pragma unroll
    for (int i = 0; i < 64; ++i) acc[i] = sB1[i];

    for (int j = 0; j < 64; j += 2) {
        const float* w0a = sW0T + j * 15;
        const float* w0b = w0a + 15;
        float za = sB0[j], zb = sB0[j + 1];
        #pragma unroll
        for (int k = 0; k < 15; ++k) {
            za = fmaf(feat[k], w0a[k], za);
            zb = fmaf(feat[k], w0b[k], zb);
        }
        float ha = fast_tanh(za), hb = fast_tanh(zb);
        const float* w1a = sW1 + j * 64;
        const float* w1b = w1a + 64;
        #pragma unroll
        for (int i = 0; i < 64; ++i)
            acc[i] = fmaf(hb, w1b[i], fmaf(ha, w1a[i], acc[i]));
    }

    // ---------- h2, z3 (4 partial sums) ----------
    float z30 = b2v[0], z31 = 0.f, z32 = 0.f, z33 = 0.f;
    #pragma unroll
    for (int i = 0; i < 64; i += 4) {
        acc[i]     = fast_tanh(acc[i]);
        acc[i + 1] = fast_tanh(acc[i + 1]);
        acc[i + 2] = fast_tanh(acc[i + 2]);
        acc[i + 3] = fast_tanh(acc[i + 3]);
        z30 = fmaf(acc[i],     sW2[i],     z30);
        z31 = fmaf(acc[i + 1], sW2[i + 1], z31);
        z32 = fmaf(acc[i + 2], sW2[i + 2], z32);
        z33 = fmaf(acc[i + 3], sW2[i + 3], z33);
    }
    const float enc = fast_tanh((z30 + z31) + (z32 + z33));
    float x;
    {
        const volatile float* Rv = ws_R + o;    // late load: don't hold R
        x = Rv[0] - (enc * enc + EPSF);
    }

    const float lx = __logf(x);
    float psum = 0.f, csum = 0.f;
    #pragma unroll
    for (int q = 0; q < 3; ++q) {
        float aq = f1[q] * f1[q] + EPSF;
        float cq = f2[q] * f2[q] + EPSF;
        float tq = __expf(-cq * (__logf(aq) + lx));   // (a*x)^(-c)
        psum += tq;
        csum = fmaf(cq, tq, csum);
    }
    const float dpdx = -__fdividef(csum, x);

    p_s[t] = psum;
    __syncthreads();
    {
        float S = 0.f;
        for (int m = 0; m < 20; ++m) S += p_s[bl * 20 + m];
        const volatile float* fcv = ws_fc + o;  // late load: don't hold fc
        out_energy[o] = S * fcv[0];
    }

    // ---------- backward ----------
    float dz3;
    {
        const volatile float* Fv = ws_F + b;    // late load: don't hold F
        dz3 = Fv[0] * dpdx * (-2.f * enc) * (1.f - enc * enc);
    }
    #pragma unroll
    for (int i = 0; i < 64; ++i) {
        float h2 = acc[i];
        acc[i] = dz3 * sW2[i] * (1.f - h2 * h2);   // dz2
    }

    float dfeat[15];
    #pragma unroll
    for (int k = 0; k < 15; ++k) dfeat[k] = 0.f;

    for (int j = 0; j < 64; j += 2) {
        const float* w1a = sW1 + j * 64;
        const float* w1b = w1a + 64;
        float sa0 = 0.f, sa1 = 0.f, sb0 = 0.f, sb1 = 0.f;
        #pragma unroll
        for (int i = 0; i < 64; i += 2) {
            sa0 = fmaf(acc[i],     w1a[i],     sa0);
            sa1 = fmaf(acc[i + 1], w1a[i + 1], sa1);
            sb0 = fmaf(acc[i],     w1b[i],     sb0);
            sb1 = fmaf(acc[i + 1], w1b[i + 1], sb1);
        }
        float dha = sa0 + sa1, dhb = sb0 + sb1;
        const float* w0a = sW0T + j * 15;
        const float* w0b = w0a + 15;
        float za = sB0[j], zb = sB0[j + 1];             // recompute h1 pair
        #pragma unroll
        for (int k = 0; k < 15; ++k) {
            za = fmaf(feat[k], w0a[k], za);
            zb = fmaf(feat[k], w0b[k], zb);
        }
        float ha = fast_tanh(za), hb = fast_tanh(zb);
        float dza = dha * (1.f - ha * ha);
        float dzb = dhb * (1.f - hb * hb);
        #pragma unroll
        for (int k = 0; k < 15; ++k)
            dfeat[k] = fmaf(dzb, w0b[k], fmaf(dza, w0a[k], dfeat[k]));
    }

    // ---- epilogue: reload O/Nr/nd (volatile: keep live ranges short above) ----
    float O[9], Nr[9], nd0, nd1, nd2;
    {
        const volatile int* iv = ws_idx + o;
        const int idx = iv[0];
        const volatile float* Ov = orientation + (size_t)b * 9;
        const volatile float* Nv = n_or + ((size_t)b * NB + idx) * 9;
        #pragma unroll
        for (int i = 0; i < 9; ++i) O[i] = Ov[i];
        #pragma unroll
        for (int i = 0; i < 9; ++i) Nr[i] = Nv[i];
        const volatile float* nv = ws_ndn + o * 3;
        nd0 = nv[0]; nd1 = nv[1]; nd2 = nv[2];
    }

    float gdr[3];
    #pragma unroll
    for (int k = 0; k < 3; ++k)
        gdr[k] = dfeat[0] * O[k * 3] + dfeat[1] * O[k * 3 + 1] + dfeat[2] * O[k * 3 + 2]
               + dfeat[3] * Nr[k * 3] + dfeat[4] * Nr[k * 3 + 1] + dfeat[5] * Nr[k * 3 + 2];

    float ndv[3] = {nd0, nd1, nd2};
    float gO[9];
    #pragma unroll
    for (int k = 0; k < 3; ++k)
        #pragma unroll
        for (int h = 0; h < 3; ++h)
            gO[k * 3 + h] = dfeat[h] * ndv[k];      // from dr_o
    #pragma unroll
    for (int h = 0; h < 3; ++h)
        #pragma unroll
        for (int l = 0; l < 3; ++l) {
            float s = 0.f;                          // from o_no
            #pragma unroll
            for (int m = 0; m < 3; ++m) s = fmaf(dfeat[6 + l * 3 + m], Nr[h * 3 + m], s);
            gO[h * 3 + l] += s;
        }

    #pragma unroll
    for (int q = 0; q < 3; ++q) red[t][q] = gdr[q];
    #pragma unroll
    for (int q = 0; q < 9; ++q) red[t][3 + q] = gO[q];
    __syncthreads();

    for (int i = t; i < 16 * 12; i += 320) {
        int bb = i / 12, q = i % 12;
        float s = 0.f;
        for (int m = 0; m < 20; ++m) s += red[bb * 20 + m][q];
        G[bb][q] = s;
    }
    __syncthreads();

    if (t < 16) {
        const int gb = blockIdx.x * 16 + t;
        out_force[gb * 3 + 0] = G[t][0];
        out_force[gb * 3 + 1] = G[t][1];
        out_force[gb * 3 + 2] = G[t][2];
        const float* Og = orientation + (size_t)gb * 9;
        float t0 = 0.f, t1 = 0.f, t2 = 0.f;
        #pragma unroll
        for (int jj = 0; jj < 3; ++jj) {
            float u0 = G[t][3 + 0 * 3 + jj], u1 = G[t][3 + 1 * 3 + jj], u2 = G[t][3 + 2 * 3 + jj];
            float v0 = Og[0 * 3 + jj], v1 = Og[1 * 3 + jj], v2 = Og[2 * 3 + jj];
            t0 += u1 * v2 - u2 * v1;
            t1 += u2 * v0 - u0 * v2;
            t2 += u0 * v1 - u1 * v0;
        }
        out_torque[gb * 3 + 0] = t0;
        out_torque[gb * 3 + 1] = t1;
        out_torque[gb * 3 + 2] = t2;
    }
}

extern "C" void kernel_launch(void* const* d_in, const int* in_sizes, int n_in,
                              void* d_out, int out_size, void* d_ws, size_t ws_size,
                              hipStream_t stream) {
    const float* dr            = (const float*)d_in[0];
    const float* orientation   = (const float*)d_in[1];
    const float* n_orientation = (const float*)d_in[2];
    const float* W0 = (const float*)d_in[3];
    const float* b0 = (const float*)d_in[4];
    const float* W1 = (const float*)d_in[5];
    const float* b1 = (const float*)d_in[6];
    const float* W2 = (const float*)d_in[7];
    const float* b2 = (const float*)d_in[8];
    const float* f1 = (const float*)d_in[9];
    const float* f2 = (const float*)d_in[10];

    const int B = in_sizes[0] / (NB * 3);   // 32768

    float* out = (float*)d_out;
    float* out_force  = out;
    float* out_torque = out + (size_t)3 * B;
    float* out_energy = out + (size_t)6 * B;

    float* ws_R   = (float*)d_ws;                       // B*20
    float* ws_fc  = ws_R  + (size_t)B * NSEL;           // B*20
    float* ws_F   = ws_fc + (size_t)B * NSEL;           // B
    int*   ws_idx = (int*)(ws_F + B);                   // B*20
    float* ws_ndn = (float*)(ws_idx + (size_t)B * NSEL);// B*20*3
    float* ws_W0T = ws_ndn + (size_t)B * NSEL * 3;      // 960

    sel_kernel<<<B / 4, 256, 0, stream>>>(dr, W0, ws_R, ws_fc, ws_F, ws_idx, ws_ndn, ws_W0T);
    energy_kernel<<<B / 16, 320, 0, stream>>>(orientation, n_orientation,
                                              ws_W0T, b0, W1, b1, W2, b2, f1, f2,
                                              ws_R, ws_fc, ws_F, ws_idx, ws_ndn,
                                              out_force, out_torque, out_energy);
}

// Round 3
// 531.943 us; speedup vs baseline: 1.1313x; 1.1313x over previous
//
#include <hip/hip_runtime.h>

#define EPSF 1e-8f
#define RCUT 4.8f
#define NB 64
#define NSEL 20

__device__ __forceinline__ float fast_tanh(float x) {
    float e = __expf(2.0f * x);
    return 1.0f - __fdividef(2.0f, e + 1.0f);
}

// ---------------- Kernel A: norms + select 20 nearest (sorted) ----------------
extern "C" __global__ void __launch_bounds__(256)
sel_kernel(const float* __restrict__ dr, const float* __restrict__ W0,
           float* __restrict__ ws_R, float* __restrict__ ws_fc,
           float* __restrict__ ws_F, int* __restrict__ ws_idx,
           float* __restrict__ ws_ndn, float* __restrict__ ws_W0T)
{
    __shared__ float R_s[256];
    const int t = threadIdx.x;
    const int g = t >> 6;       // which b within block (0..3)
    const int j = t & 63;       // neighbor id
    const int b = blockIdx.x * 4 + g;

    const float* p = dr + ((size_t)b * NB + j) * 3;
    float x = p[0] + EPSF, y = p[1] + EPSF, z = p[2] + EPSF;
    float R = sqrtf(x * x + y * y + z * z);
    R_s[t] = R;
    __syncthreads();

    // stable rank: count (Rk < R) or (Rk == R and k < j)
    int rank = 0;
    const float* grp = R_s + g * 64;
    #pragma unroll 8
    for (int k = 0; k < 64; ++k) {
        float Rk = grp[k];
        rank += (Rk < R || (Rk == R && k < j)) ? 1 : 0;
    }

    float fc = 0.0f;
    if (rank < NSEL) {
        fc = (R > RCUT) ? 0.0f
                        : (0.5f * __cosf(3.14159265358979323846f * R / RCUT) + 0.5f);
        size_t o = (size_t)b * NSEL + rank;
        ws_R[o]  = R;
        ws_fc[o] = fc;
        ws_idx[o] = j;
        float inv = 1.0f / R;
        ws_ndn[o * 3 + 0] = x * inv;
        ws_ndn[o * 3 + 1] = y * inv;
        ws_ndn[o * 3 + 2] = z * inv;
    }

    // F[b] = sum of selected fc over this wave (each group is exactly one wave)
    float F = fc;
    for (int off = 32; off > 0; off >>= 1) F += __shfl_xor(F, off, 64);
    if (j == 0) ws_F[b] = F;

    // one-time W0 transpose (block 0 only; A always runs before B on the stream)
    if (blockIdx.x == 0) {
        for (int i = t; i < 15 * 64; i += 256) {
            int k = i >> 6, jj = i & 63;
            ws_W0T[jj * 15 + k] = W0[i];
        }
    }
}

// ---------------- Kernel B: per-pair MLP fwd + analytic bwd ----------------
// (320,4): cap 128 total regs/wave (acc[64] in AGPRs + <=64 arch) so 3 blocks/CU
// co-reside.
// R6: stage ONLY W1 (16KB) in LDS. R5 (all weights in LDS) spilled ~25 regs to
// scratch (WRITE_SIZE 7.9->72MB, dur 400->535us): staging addr state overlapped
// feat/O/Nr live ranges under the 128-reg cap. Fix: W1 staged via a bare float4
// loop at the TOP (no other live state), __syncthreads, THEN feat. W0T+biases
// (~4.3KB) stay in global -- they fit the 16KB scalar K$ once W1 (16KB, the
// thrasher) is out of the scalar path. LDS total ~33.4KB -> 4 blocks/CU by LDS,
// register limit (3 blocks) still binds.
extern "C" __global__ void __launch_bounds__(320, 4)
energy_kernel(const float* __restrict__ orientation, const float* __restrict__ n_or,
              const float* __restrict__ W0T, const float* __restrict__ b0,
              const float* __restrict__ W1, const float* __restrict__ b1,
              const float* __restrict__ W2, const float* __restrict__ b2v,
              const float* __restrict__ f1, const float* __restrict__ f2,
              const float* __restrict__ ws_R, const float* __restrict__ ws_fc,
              const float* __restrict__ ws_F, const int* __restrict__ ws_idx,
              const float* __restrict__ ws_ndn,
              float* __restrict__ out_force, float* __restrict__ out_torque,
              float* __restrict__ out_energy)
{
    __shared__ float sW1[64 * 64];     // 16 KB [j][i]
    __shared__ float p_s[320];
    __shared__ float red[320][12];
    __shared__ float G[16][12];

    const int t = threadIdx.x;

    // ---- stage W1 to LDS first: no other live state during this loop ----
    {
        const float4* src = (const float4*)W1;
        float4* dst = (float4*)sW1;
        for (int i = t; i < 1024; i += 320) dst[i] = src[i];
    }
    __syncthreads();

    const int bl = t / 20;      // local b (0..15)
    const int n  = t % 20;      // selected-neighbor slot
    const int b  = blockIdx.x * 16 + bl;
    const size_t o = (size_t)b * NSEL + n;

    // feat = [dr_o(3), dr_no(3), o_no(9)]; O/Nr/nd scoped so they die here.
    float feat[15];
    {
        const float nd0 = ws_ndn[o * 3 + 0];
        const float nd1 = ws_ndn[o * 3 + 1];
        const float nd2 = ws_ndn[o * 3 + 2];
        const int  idx = ws_idx[o];
        float O[9], Nr[9];
        const float* Op = orientation + (size_t)b * 9;
        #pragma unroll
        for (int i = 0; i < 9; ++i) O[i] = Op[i];
        const float* Np = n_or + ((size_t)b * NB + idx) * 9;
        #pragma unroll
        for (int i = 0; i < 9; ++i) Nr[i] = Np[i];

        #pragma unroll
        for (int h = 0; h < 3; ++h)
            feat[h] = nd0 * O[h] + nd1 * O[3 + h] + nd2 * O[6 + h];
        #pragma unroll
        for (int h = 0; h < 3; ++h)
            feat[3 + h] = nd0 * Nr[h] + nd1 * Nr[3 + h] + nd2 * Nr[6 + h];
        #pragma unroll
        for (int l = 0; l < 3; ++l)
            #pragma unroll
            for (int m = 0; m < 3; ++m)
                feat[6 + l * 3 + m] = O[l] * Nr[m] + O[3 + l] * Nr[3 + m] + O[6 + l] * Nr[6 + m];
    }

    // ---------- forward (j, j+1 interleaved for 2x ILP on the serial chain) ----
    float acc[64];                      // z2 accumulators -> h2 -> dz2 (in place)
    #pragma unroll
    for (int i = 0; i < 64; ++i) acc[i] = b1[i];

    for (int j = 0; j < 64; j += 2) {
        const float* w0a = W0T + j * 15;
        const float* w0b = w0a + 15;
        float za = b0[j], zb = b0[j + 1];
        #pragma unroll
        for (int k = 0; k < 15; ++k) {
            za = fmaf(feat[k], w0a[k], za);
            zb = fmaf(feat[k], w0b[k], zb);
        }
        float ha = fast_tanh(za), hb = fast_tanh(zb);
        const float* w1a = sW1 + j * 64;
        const float* w1b = w1a + 64;
        #pragma unroll
        for (int i = 0; i < 64; ++i)
            acc[i] = fmaf(hb, w1b[i], fmaf(ha, w1a[i], acc[i]));
    }

    // ---------- h2, z3 (4 partial sums) ----------
    float z30 = b2v[0], z31 = 0.f, z32 = 0.f, z33 = 0.f;
    #pragma unroll
    for (int i = 0; i < 64; i += 4) {
        acc[i]     = fast_tanh(acc[i]);
        acc[i + 1] = fast_tanh(acc[i + 1]);
        acc[i + 2] = fast_tanh(acc[i + 2]);
        acc[i + 3] = fast_tanh(acc[i + 3]);
        z30 = fmaf(acc[i],     W2[i],     z30);
        z31 = fmaf(acc[i + 1], W2[i + 1], z31);
        z32 = fmaf(acc[i + 2], W2[i + 2], z32);
        z33 = fmaf(acc[i + 3], W2[i + 3], z33);
    }
    const float enc = fast_tanh((z30 + z31) + (z32 + z33));
    float x;
    {
        const volatile float* Rv = ws_R + o;    // late load: don't hold R
        x = Rv[0] - (enc * enc + EPSF);
    }

    const float lx = __logf(x);
    float psum = 0.f, csum = 0.f;
    #pragma unroll
    for (int q = 0; q < 3; ++q) {
        float aq = f1[q] * f1[q] + EPSF;
        float cq = f2[q] * f2[q] + EPSF;
        float tq = __expf(-cq * (__logf(aq) + lx));   // (a*x)^(-c)
        psum += tq;
        csum = fmaf(cq, tq, csum);
    }
    const float dpdx = -__fdividef(csum, x);

    p_s[t] = psum;
    __syncthreads();
    {
        float S = 0.f;
        for (int m = 0; m < 20; ++m) S += p_s[bl * 20 + m];
        const volatile float* fcv = ws_fc + o;  // late load: don't hold fc
        out_energy[o] = S * fcv[0];
    }

    // ---------- backward ----------
    float dz3;
    {
        const volatile float* Fv = ws_F + b;    // late load: don't hold F
        dz3 = Fv[0] * dpdx * (-2.f * enc) * (1.f - enc * enc);
    }
    #pragma unroll
    for (int i = 0; i < 64; ++i) {
        float h2 = acc[i];
        acc[i] = dz3 * W2[i] * (1.f - h2 * h2);   // dz2
    }

    float dfeat[15];
    #pragma unroll
    for (int k = 0; k < 15; ++k) dfeat[k] = 0.f;

    for (int j = 0; j < 64; j += 2) {
        const float* w1a = sW1 + j * 64;
        const float* w1b = w1a + 64;
        float sa0 = 0.f, sa1 = 0.f, sb0 = 0.f, sb1 = 0.f;
        #pragma unroll
        for (int i = 0; i < 64; i += 2) {
            sa0 = fmaf(acc[i],     w1a[i],     sa0);
            sa1 = fmaf(acc[i + 1], w1a[i + 1], sa1);
            sb0 = fmaf(acc[i],     w1b[i],     sb0);
            sb1 = fmaf(acc[i + 1], w1b[i + 1], sb1);
        }
        float dha = sa0 + sa1, dhb = sb0 + sb1;
        const float* w0a = W0T + j * 15;
        const float* w0b = w0a + 15;
        float za = b0[j], zb = b0[j + 1];               // recompute h1 pair
        #pragma unroll
        for (int k = 0; k < 15; ++k) {
            za = fmaf(feat[k], w0a[k], za);
            zb = fmaf(feat[k], w0b[k], zb);
        }
        float ha = fast_tanh(za), hb = fast_tanh(zb);
        float dza = dha * (1.f - ha * ha);
        float dzb = dhb * (1.f - hb * hb);
        #pragma unroll
        for (int k = 0; k < 15; ++k)
            dfeat[k] = fmaf(dzb, w0b[k], fmaf(dza, w0a[k], dfeat[k]));
    }

    // ---- epilogue: reload O/Nr/nd (volatile: keep live ranges short above) ----
    float O[9], Nr[9], nd0, nd1, nd2;
    {
        const volatile int* iv = ws_idx + o;
        const int idx = iv[0];
        const volatile float* Ov = orientation + (size_t)b * 9;
        const volatile float* Nv = n_or + ((size_t)b * NB + idx) * 9;
        #pragma unroll
        for (int i = 0; i < 9; ++i) O[i] = Ov[i];
        #pragma unroll
        for (int i = 0; i < 9; ++i) Nr[i] = Nv[i];
        const volatile float* nv = ws_ndn + o * 3;
        nd0 = nv[0]; nd1 = nv[1]; nd2 = nv[2];
    }

    float gdr[3];
    #pragma unroll
    for (int k = 0; k < 3; ++k)
        gdr[k] = dfeat[0] * O[k * 3] + dfeat[1] * O[k * 3 + 1] + dfeat[2] * O[k * 3 + 2]
               + dfeat[3] * Nr[k * 3] + dfeat[4] * Nr[k * 3 + 1] + dfeat[5] * Nr[k * 3 + 2];

    float ndv[3] = {nd0, nd1, nd2};
    float gO[9];
    #pragma unroll
    for (int k = 0; k < 3; ++k)
        #pragma unroll
        for (int h = 0; h < 3; ++h)
            gO[k * 3 + h] = dfeat[h] * ndv[k];      // from dr_o
    #pragma unroll
    for (int h = 0; h < 3; ++h)
        #pragma unroll
        for (int l = 0; l < 3; ++l) {
            float s = 0.f;                          // from o_no
            #pragma unroll
            for (int m = 0; m < 3; ++m) s = fmaf(dfeat[6 + l * 3 + m], Nr[h * 3 + m], s);
            gO[h * 3 + l] += s;
        }

    #pragma unroll
    for (int q = 0; q < 3; ++q) red[t][q] = gdr[q];
    #pragma unroll
    for (int q = 0; q < 9; ++q) red[t][3 + q] = gO[q];
    __syncthreads();

    for (int i = t; i < 16 * 12; i += 320) {
        int bb = i / 12, q = i % 12;
        float s = 0.f;
        for (int m = 0; m < 20; ++m) s += red[bb * 20 + m][q];
        G[bb][q] = s;
    }
    __syncthreads();

    if (t < 16) {
        const int gb = blockIdx.x * 16 + t;
        out_force[gb * 3 + 0] = G[t][0];
        out_force[gb * 3 + 1] = G[t][1];
        out_force[gb * 3 + 2] = G[t][2];
        const float* Og = orientation + (size_t)gb * 9;
        float t0 = 0.f, t1 = 0.f, t2 = 0.f;
        #pragma unroll
        for (int jj = 0; jj < 3; ++jj) {
            float u0 = G[t][3 + 0 * 3 + jj], u1 = G[t][3 + 1 * 3 + jj], u2 = G[t][3 + 2 * 3 + jj];
            float v0 = Og[0 * 3 + jj], v1 = Og[1 * 3 + jj], v2 = Og[2 * 3 + jj];
            t0 += u1 * v2 - u2 * v1;
            t1 += u2 * v0 - u0 * v2;
            t2 += u0 * v1 - u1 * v0;
        }
        out_torque[gb * 3 + 0] = t0;
        out_torque[gb * 3 + 1] = t1;
        out_torque[gb * 3 + 2] = t2;
    }
}

extern "C" void kernel_launch(void* const* d_in, const int* in_sizes, int n_in,
                              void* d_out, int out_size, void* d_ws, size_t ws_size,
                              hipStream_t stream) {
    const float* dr            = (const float*)d_in[0];
    const float* orientation   = (const float*)d_in[1];
    const float* n_orientation = (const float*)d_in[2];
    const float* W0 = (const float*)d_in[3];
    const float* b0 = (const float*)d_in[4];
    const float* W1 = (const float*)d_in[5];
    const float* b1 = (const float*)d_in[6];
    const float* W2 = (const float*)d_in[7];
    const float* b2 = (const float*)d_in[8];
    const float* f1 = (const float*)d_in[9];
    const float* f2 = (const float*)d_in[10];

    const int B = in_sizes[0] / (NB * 3);   // 32768

    float* out = (float*)d_out;
    float* out_force  = out;
    float* out_torque = out + (size_t)3 * B;
    float* out_energy = out + (size_t)6 * B;

    float* ws_R   = (float*)d_ws;                       // B*20
    float* ws_fc  = ws_R  + (size_t)B * NSEL;           // B*20
    float* ws_F   = ws_fc + (size_t)B * NSEL;           // B
    int*   ws_idx = (int*)(ws_F + B);                   // B*20
    float* ws_ndn = (float*)(ws_idx + (size_t)B * NSEL);// B*20*3
    float* ws_W0T = ws_ndn + (size_t)B * NSEL * 3;      // 960

    sel_kernel<<<B / 4, 256, 0, stream>>>(dr, W0, ws_R, ws_fc, ws_F, ws_idx, ws_ndn, ws_W0T);
    energy_kernel<<<B / 16, 320, 0, stream>>>(orientation, n_orientation,
                                              ws_W0T, b0, W1, b1, W2, b2, f1, f2,
                                              ws_R, ws_fc, ws_F, ws_idx, ws_ndn,
                                              out_force, out_torque, out_energy);
}

// Round 4
// 502.033 us; speedup vs baseline: 1.1987x; 1.0596x over previous
//
#include <hip/hip_runtime.h>

#define EPSF 1e-8f
#define RCUT 4.8f
#define NB 64
#define NSEL 20

__device__ __forceinline__ float fast_tanh(float x) {
    float e = __expf(2.0f * x);
    return 1.0f - __fdividef(2.0f, e + 1.0f);
}

// ---------------- Kernel A: norms + select 20 nearest + pre-gather n_or -------
// R7: also copies the selected n_or rows to compact ws_nor (coalesced read:
// lane j reads row j of its b -- 2304B contiguous per wave). This moves the
// random 36B/thread HBM gather out of the latency-sensitive energy kernel.
extern "C" __global__ void __launch_bounds__(256)
sel_kernel(const float* __restrict__ dr, const float* __restrict__ n_or,
           const float* __restrict__ W0,
           float* __restrict__ ws_R, float* __restrict__ ws_fc,
           float* __restrict__ ws_F, int* __restrict__ ws_idx,
           float* __restrict__ ws_ndn, float* __restrict__ ws_W0T,
           float* __restrict__ ws_nor)
{
    __shared__ float R_s[256];
    const int t = threadIdx.x;
    const int g = t >> 6;       // which b within block (0..3)
    const int j = t & 63;       // neighbor id
    const int b = blockIdx.x * 4 + g;

    const float* p = dr + ((size_t)b * NB + j) * 3;
    float x = p[0] + EPSF, y = p[1] + EPSF, z = p[2] + EPSF;
    float R = sqrtf(x * x + y * y + z * z);
    R_s[t] = R;
    __syncthreads();

    // stable rank: count (Rk < R) or (Rk == R and k < j)
    int rank = 0;
    const float* grp = R_s + g * 64;
    #pragma unroll 8
    for (int k = 0; k < 64; ++k) {
        float Rk = grp[k];
        rank += (Rk < R || (Rk == R && k < j)) ? 1 : 0;
    }

    float fc = 0.0f;
    if (rank < NSEL) {
        fc = (R > RCUT) ? 0.0f
                        : (0.5f * __cosf(3.14159265358979323846f * R / RCUT) + 0.5f);
        size_t o = (size_t)b * NSEL + rank;
        ws_R[o]  = R;
        ws_fc[o] = fc;
        ws_idx[o] = j;
        float inv = 1.0f / R;
        ws_ndn[o * 3 + 0] = x * inv;
        ws_ndn[o * 3 + 1] = y * inv;
        ws_ndn[o * 3 + 2] = z * inv;
    }

    // pre-gather selected n_or rows into compact ws_nor (coalesced read)
    if (ws_nor) {
        const float* np = n_or + ((size_t)b * NB + j) * 9;
        float r[9];
        #pragma unroll
        for (int q = 0; q < 9; ++q) r[q] = np[q];
        if (rank < NSEL) {
            float* dst = ws_nor + ((size_t)b * NSEL + rank) * 9;
            #pragma unroll
            for (int q = 0; q < 9; ++q) dst[q] = r[q];
        }
    }

    // F[b] = sum of selected fc over this wave (each group is exactly one wave)
    float F = fc;
    for (int off = 32; off > 0; off >>= 1) F += __shfl_xor(F, off, 64);
    if (j == 0) ws_F[b] = F;

    // one-time W0 transpose, rows padded to 16 floats (64B-aligned s_loads)
    if (blockIdx.x == 0) {
        for (int i = t; i < 15 * 64; i += 256) {
            int k = i >> 6, jj = i & 63;
            ws_W0T[jj * 16 + k] = W0[i];
        }
    }
}

// ---------------- Kernel B: per-pair MLP fwd + analytic bwd ----------------
// (320,4): 128 total regs/wave (acc[64] AGPR + <=64 arch), 3 blocks/CU.
// R5/R6 lesson: LDS weight staging forces the weight stream through VGPRs
// (ds_read dests) -> spills at the 128-reg cap (WRITE_SIZE 8->72/23MB, dur
// 400->535/460). Scalar K$->SGPR weight path (R0) is structurally right: SGPR
// FMA operands are free. Reverted.
// R7: kill the n_or random HBM gather (FETCH 43MB, ~900cy misses, done 2x/thread):
// PRE variant reads compact ws_nor (coalesced); both variants stash Nr in LDS
// (own-slot, stride 9 -> 2 lanes/bank = conflict-free) so the epilogue never
// re-gathers from global. W0T stride 16 (aligned rows).
template<bool PRE>
__global__ void __launch_bounds__(320, 4)
energy_kernel_t(const float* __restrict__ orientation, const float* __restrict__ n_or,
              const float* __restrict__ W0T, const float* __restrict__ b0,
              const float* __restrict__ W1, const float* __restrict__ b1,
              const float* __restrict__ W2, const float* __restrict__ b2v,
              const float* __restrict__ f1, const float* __restrict__ f2,
              const float* __restrict__ ws_R, const float* __restrict__ ws_fc,
              const float* __restrict__ ws_F, const int* __restrict__ ws_idx,
              const float* __restrict__ ws_ndn, const float* __restrict__ ws_nor,
              float* __restrict__ out_force, float* __restrict__ out_torque,
              float* __restrict__ out_energy)
{
    __shared__ float sNr[320 * 9];     // 11.25 KB per-thread Nr stash
    __shared__ float p_s[320];
    __shared__ float red[320][12];
    __shared__ float G[16][12];

    const int t = threadIdx.x;
    const int bl = t / 20;      // local b (0..15)
    const int n  = t % 20;      // selected-neighbor slot
    const int b  = blockIdx.x * 16 + bl;
    const size_t o = (size_t)b * NSEL + n;

    // feat = [dr_o(3), dr_no(3), o_no(9)]; O/Nr/nd scoped so they die here.
    float feat[15];
    {
        const float nd0 = ws_ndn[o * 3 + 0];
        const float nd1 = ws_ndn[o * 3 + 1];
        const float nd2 = ws_ndn[o * 3 + 2];
        float O[9], Nr[9];
        const float* Op = orientation + (size_t)b * 9;
        #pragma unroll
        for (int i = 0; i < 9; ++i) O[i] = Op[i];
        if (PRE) {
            const float* Np = ws_nor + o * 9;
            #pragma unroll
            for (int i = 0; i < 9; ++i) Nr[i] = Np[i];
        } else {
            const int idx = ws_idx[o];
            const float* Np = n_or + ((size_t)b * NB + idx) * 9;
            #pragma unroll
            for (int i = 0; i < 9; ++i) Nr[i] = Np[i];
        }
        // stash Nr for the epilogue (same thread reads it back: no barrier)
        #pragma unroll
        for (int q = 0; q < 9; ++q) sNr[t * 9 + q] = Nr[q];

        #pragma unroll
        for (int h = 0; h < 3; ++h)
            feat[h] = nd0 * O[h] + nd1 * O[3 + h] + nd2 * O[6 + h];
        #pragma unroll
        for (int h = 0; h < 3; ++h)
            feat[3 + h] = nd0 * Nr[h] + nd1 * Nr[3 + h] + nd2 * Nr[6 + h];
        #pragma unroll
        for (int l = 0; l < 3; ++l)
            #pragma unroll
            for (int m = 0; m < 3; ++m)
                feat[6 + l * 3 + m] = O[l] * Nr[m] + O[3 + l] * Nr[3 + m] + O[6 + l] * Nr[6 + m];
    }

    // ---------- forward (j, j+1 interleaved for 2x ILP on the serial chain) ----
    float acc[64];                      // z2 accumulators -> h2 -> dz2 (in place)
    #pragma unroll
    for (int i = 0; i < 64; ++i) acc[i] = b1[i];

    for (int j = 0; j < 64; j += 2) {
        const float* w0a = W0T + j * 16;
        const float* w0b = w0a + 16;
        float za = b0[j], zb = b0[j + 1];
        #pragma unroll
        for (int k = 0; k < 15; ++k) {
            za = fmaf(feat[k], w0a[k], za);
            zb = fmaf(feat[k], w0b[k], zb);
        }
        float ha = fast_tanh(za), hb = fast_tanh(zb);
        const float* w1a = W1 + j * 64;
        const float* w1b = w1a + 64;
        #pragma unroll
        for (int i = 0; i < 64; ++i)
            acc[i] = fmaf(hb, w1b[i], fmaf(ha, w1a[i], acc[i]));
    }

    // ---------- h2, z3 (4 partial sums) ----------
    float z30 = b2v[0], z31 = 0.f, z32 = 0.f, z33 = 0.f;
    #pragma unroll
    for (int i = 0; i < 64; i += 4) {
        acc[i]     = fast_tanh(acc[i]);
        acc[i + 1] = fast_tanh(acc[i + 1]);
        acc[i + 2] = fast_tanh(acc[i + 2]);
        acc[i + 3] = fast_tanh(acc[i + 3]);
        z30 = fmaf(acc[i],     W2[i],     z30);
        z31 = fmaf(acc[i + 1], W2[i + 1], z31);
        z32 = fmaf(acc[i + 2], W2[i + 2], z32);
        z33 = fmaf(acc[i + 3], W2[i + 3], z33);
    }
    const float enc = fast_tanh((z30 + z31) + (z32 + z33));
    float x;
    {
        const volatile float* Rv = ws_R + o;    // late load: don't hold R
        x = Rv[0] - (enc * enc + EPSF);
    }

    const float lx = __logf(x);
    float psum = 0.f, csum = 0.f;
    #pragma unroll
    for (int q = 0; q < 3; ++q) {
        float aq = f1[q] * f1[q] + EPSF;
        float cq = f2[q] * f2[q] + EPSF;
        float tq = __expf(-cq * (__logf(aq) + lx));   // (a*x)^(-c)
        psum += tq;
        csum = fmaf(cq, tq, csum);
    }
    const float dpdx = -__fdividef(csum, x);

    p_s[t] = psum;
    __syncthreads();
    {
        float S = 0.f;
        for (int m = 0; m < 20; ++m) S += p_s[bl * 20 + m];
        const volatile float* fcv = ws_fc + o;  // late load: don't hold fc
        out_energy[o] = S * fcv[0];
    }

    // ---------- backward ----------
    float dz3;
    {
        const volatile float* Fv = ws_F + b;    // late load: don't hold F
        dz3 = Fv[0] * dpdx * (-2.f * enc) * (1.f - enc * enc);
    }
    #pragma unroll
    for (int i = 0; i < 64; ++i) {
        float h2 = acc[i];
        acc[i] = dz3 * W2[i] * (1.f - h2 * h2);   // dz2
    }

    float dfeat[15];
    #pragma unroll
    for (int k = 0; k < 15; ++k) dfeat[k] = 0.f;

    for (int j = 0; j < 64; j += 2) {
        const float* w1a = W1 + j * 64;
        const float* w1b = w1a + 64;
        float sa0 = 0.f, sa1 = 0.f, sb0 = 0.f, sb1 = 0.f;
        #pragma unroll
        for (int i = 0; i < 64; i += 2) {
            sa0 = fmaf(acc[i],     w1a[i],     sa0);
            sa1 = fmaf(acc[i + 1], w1a[i + 1], sa1);
            sb0 = fmaf(acc[i],     w1b[i],     sb0);
            sb1 = fmaf(acc[i + 1], w1b[i + 1], sb1);
        }
        float dha = sa0 + sa1, dhb = sb0 + sb1;
        const float* w0a = W0T + j * 16;
        const float* w0b = w0a + 16;
        float za = b0[j], zb = b0[j + 1];               // recompute h1 pair
        #pragma unroll
        for (int k = 0; k < 15; ++k) {
            za = fmaf(feat[k], w0a[k], za);
            zb = fmaf(feat[k], w0b[k], zb);
        }
        float ha = fast_tanh(za), hb = fast_tanh(zb);
        float dza = dha * (1.f - ha * ha);
        float dzb = dhb * (1.f - hb * hb);
        #pragma unroll
        for (int k = 0; k < 15; ++k)
            dfeat[k] = fmaf(dzb, w0b[k], fmaf(dza, w0a[k], dfeat[k]));
    }

    // ---- epilogue: O/nd reloaded (volatile, L2-cheap); Nr from LDS stash ----
    float O[9], Nr[9], nd0, nd1, nd2;
    {
        const volatile float* Ov = orientation + (size_t)b * 9;
        #pragma unroll
        for (int i = 0; i < 9; ++i) O[i] = Ov[i];
        volatile float* sv = sNr + t * 9;
        #pragma unroll
        for (int i = 0; i < 9; ++i) Nr[i] = sv[i];
        const volatile float* nv = ws_ndn + o * 3;
        nd0 = nv[0]; nd1 = nv[1]; nd2 = nv[2];
    }

    float gdr[3];
    #pragma unroll
    for (int k = 0; k < 3; ++k)
        gdr[k] = dfeat[0] * O[k * 3] + dfeat[1] * O[k * 3 + 1] + dfeat[2] * O[k * 3 + 2]
               + dfeat[3] * Nr[k * 3] + dfeat[4] * Nr[k * 3 + 1] + dfeat[5] * Nr[k * 3 + 2];

    float ndv[3] = {nd0, nd1, nd2};
    float gO[9];
    #pragma unroll
    for (int k = 0; k < 3; ++k)
        #pragma unroll
        for (int h = 0; h < 3; ++h)
            gO[k * 3 + h] = dfeat[h] * ndv[k];      // from dr_o
    #pragma unroll
    for (int h = 0; h < 3; ++h)
        #pragma unroll
        for (int l = 0; l < 3; ++l) {
            float s = 0.f;                          // from o_no
            #pragma unroll
            for (int m = 0; m < 3; ++m) s = fmaf(dfeat[6 + l * 3 + m], Nr[h * 3 + m], s);
            gO[h * 3 + l] += s;
        }

    #pragma unroll
    for (int q = 0; q < 3; ++q) red[t][q] = gdr[q];
    #pragma unroll
    for (int q = 0; q < 9; ++q) red[t][3 + q] = gO[q];
    __syncthreads();

    for (int i = t; i < 16 * 12; i += 320) {
        int bb = i / 12, q = i % 12;
        float s = 0.f;
        for (int m = 0; m < 20; ++m) s += red[bb * 20 + m][q];
        G[bb][q] = s;
    }
    __syncthreads();

    if (t < 16) {
        const int gb = blockIdx.x * 16 + t;
        out_force[gb * 3 + 0] = G[t][0];
        out_force[gb * 3 + 1] = G[t][1];
        out_force[gb * 3 + 2] = G[t][2];
        const float* Og = orientation + (size_t)gb * 9;
        float t0 = 0.f, t1 = 0.f, t2 = 0.f;
        #pragma unroll
        for (int jj = 0; jj < 3; ++jj) {
            float u0 = G[t][3 + 0 * 3 + jj], u1 = G[t][3 + 1 * 3 + jj], u2 = G[t][3 + 2 * 3 + jj];
            float v0 = Og[0 * 3 + jj], v1 = Og[1 * 3 + jj], v2 = Og[2 * 3 + jj];
            t0 += u1 * v2 - u2 * v1;
            t1 += u2 * v0 - u0 * v2;
            t2 += u0 * v1 - u1 * v0;
        }
        out_torque[gb * 3 + 0] = t0;
        out_torque[gb * 3 + 1] = t1;
        out_torque[gb * 3 + 2] = t2;
    }
}

extern "C" void kernel_launch(void* const* d_in, const int* in_sizes, int n_in,
                              void* d_out, int out_size, void* d_ws, size_t ws_size,
                              hipStream_t stream) {
    const float* dr            = (const float*)d_in[0];
    const float* orientation   = (const float*)d_in[1];
    const float* n_orientation = (const float*)d_in[2];
    const float* W0 = (const float*)d_in[3];
    const float* b0 = (const float*)d_in[4];
    const float* W1 = (const float*)d_in[5];
    const float* b1 = (const float*)d_in[6];
    const float* W2 = (const float*)d_in[7];
    const float* b2 = (const float*)d_in[8];
    const float* f1 = (const float*)d_in[9];
    const float* f2 = (const float*)d_in[10];

    const int B = in_sizes[0] / (NB * 3);   // 32768

    float* out = (float*)d_out;
    float* out_force  = out;
    float* out_torque = out + (size_t)3 * B;
    float* out_energy = out + (size_t)6 * B;

    float* ws_R   = (float*)d_ws;                        // B*20
    float* ws_fc  = ws_R   + (size_t)B * NSEL;           // B*20
    float* ws_F   = ws_fc  + (size_t)B * NSEL;           // B
    int*   ws_idx = (int*)(ws_F + B);                    // B*20
    float* ws_ndn = (float*)(ws_idx + (size_t)B * NSEL); // B*20*3
    float* ws_W0T = ws_ndn + (size_t)B * NSEL * 3;       // 64*16 = 1024
    float* ws_nor = ws_W0T + 1024;                       // B*20*9 (optional)

    const size_t needed_full = sizeof(float) *
        ((size_t)B * (NSEL * (1 + 1 + 1 + 3 + 9)) + (size_t)B + 1024);
    const bool pre = ws_size >= needed_full;

    sel_kernel<<<B / 4, 256, 0, stream>>>(dr, n_orientation, W0,
                                          ws_R, ws_fc, ws_F, ws_idx, ws_ndn, ws_W0T,
                                          pre ? ws_nor : nullptr);
    if (pre) {
        energy_kernel_t<true><<<B / 16, 320, 0, stream>>>(orientation, n_orientation,
            ws_W0T, b0, W1, b1, W2, b2, f1, f2,
            ws_R, ws_fc, ws_F, ws_idx, ws_ndn, ws_nor,
            out_force, out_torque, out_energy);
    } else {
        energy_kernel_t<false><<<B / 16, 320, 0, stream>>>(orientation, n_orientation,
            ws_W0T, b0, W1, b1, W2, b2, f1, f2,
            ws_R, ws_fc, ws_F, ws_idx, ws_ndn, ws_nor,
            out_force, out_torque, out_energy);
    }
}

// Round 6
// 476.137 us; speedup vs baseline: 1.2639x; 1.0544x over previous
//
#include <hip/hip_runtime.h>

#define EPSF 1e-8f
#define RCUT 4.8f
#define NB 64
#define NSEL 20

// ---- weights blob layout (float offsets inside wsW) ----
#define OW0T 0        // 64 rows x 16 (transposed W0, row-padded)
#define OB0  1024     // 64
#define OB1  1088     // 64
#define OW2  1152     // 64
#define OB2  1216     // 1
#define OAQ  1220     // 3: f1^2+eps
#define OCQ  1224     // 3: f2^2+eps
#define OLG  1228     // 3: log(aq)
#define OW1  1232     // 64x64
#define WSWN 5328     // total floats

__device__ __forceinline__ float fast_tanh(float x) {
    float e = __expf(2.0f * x);
    return 1.0f - __fdividef(2.0f, e + 1.0f);
}

// ---------------- Kernel A: norms + select 20 nearest + pre-gather ----------
// R8: block 0 additionally packs ALL weights (+ precomputed aq/cq/log(aq))
// into one blob so energy needs ~4 live pointer args (kernarg SGPR diet:
// R3 showed SGPR_Count=112 == ceiling -> s_load prefetch depth starved).
extern "C" __global__ void __launch_bounds__(256)
sel_kernel(const float* __restrict__ dr, const float* __restrict__ n_or,
           const float* __restrict__ W0, const float* __restrict__ b0,
           const float* __restrict__ W1, const float* __restrict__ b1,
           const float* __restrict__ W2, const float* __restrict__ b2,
           const float* __restrict__ f1, const float* __restrict__ f2,
           float* __restrict__ ws_R, float* __restrict__ ws_fc,
           float* __restrict__ ws_F, int* __restrict__ ws_idx,
           float* __restrict__ ws_ndn, float* __restrict__ ws_nor,
           float* __restrict__ wsW)
{
    __shared__ float R_s[256];
    const int t = threadIdx.x;
    const int g = t >> 6;       // which b within block (0..3)
    const int j = t & 63;       // neighbor id
    const int b = blockIdx.x * 4 + g;

    const float* p = dr + ((size_t)b * NB + j) * 3;
    float x = p[0] + EPSF, y = p[1] + EPSF, z = p[2] + EPSF;
    float R = sqrtf(x * x + y * y + z * z);
    R_s[t] = R;
    __syncthreads();

    // stable rank: count (Rk < R) or (Rk == R and k < j)
    int rank = 0;
    const float* grp = R_s + g * 64;
    #pragma unroll 8
    for (int k = 0; k < 64; ++k) {
        float Rk = grp[k];
        rank += (Rk < R || (Rk == R && k < j)) ? 1 : 0;
    }

    float fc = 0.0f;
    if (rank < NSEL) {
        fc = (R > RCUT) ? 0.0f
                        : (0.5f * __cosf(3.14159265358979323846f * R / RCUT) + 0.5f);
        size_t o = (size_t)b * NSEL + rank;
        ws_R[o]  = R;
        ws_fc[o] = fc;
        if (ws_idx) ws_idx[o] = j;
        float inv = 1.0f / R;
        ws_ndn[o * 3 + 0] = x * inv;
        ws_ndn[o * 3 + 1] = y * inv;
        ws_ndn[o * 3 + 2] = z * inv;
    }

    // pre-gather selected n_or rows into compact ws_nor (coalesced read)
    if (ws_nor) {
        const float* np = n_or + ((size_t)b * NB + j) * 9;
        float r[9];
        #pragma unroll
        for (int q = 0; q < 9; ++q) r[q] = np[q];
        if (rank < NSEL) {
            float* dst = ws_nor + ((size_t)b * NSEL + rank) * 9;
            #pragma unroll
            for (int q = 0; q < 9; ++q) dst[q] = r[q];
        }
    }

    // F[b] = sum of selected fc over this wave (each group is exactly one wave)
    float F = fc;
    for (int off = 32; off > 0; off >>= 1) F += __shfl_xor(F, off, 64);
    if (j == 0) ws_F[b] = F;

    // one-time weights blob fill (block 0; A completes before B on the stream)
    if (blockIdx.x == 0) {
        for (int i = t; i < 15 * 64; i += 256) {          // W0 transpose, stride 16
            int k = i >> 6, jj = i & 63;
            wsW[OW0T + jj * 16 + k] = W0[i];
        }
        for (int i = t; i < 64 * 64; i += 256)            // W1 verbatim
            wsW[OW1 + i] = W1[i];
        if (t < 64) {
            wsW[OB0 + t] = b0[t];
            wsW[OB1 + t] = b1[t];
            wsW[OW2 + t] = W2[t];
        }
        if (t == 0) wsW[OB2] = b2[0];
        if (t < 3) {
            float a = f1[t] * f1[t] + EPSF;
            float c = f2[t] * f2[t] + EPSF;
            wsW[OAQ + t] = a;
            wsW[OCQ + t] = c;
            wsW[OLG + t] = __logf(a);
        }
    }
}

// ---------------- Kernel B: per-pair MLP fwd + analytic bwd ----------------
// (320,4): 128 total regs/wave (acc[64] AGPR + <=64 arch), 3 blocks/CU.
// R5/R6 lesson: LDS weight staging forces weights through VGPRs -> spills at
// the 128-reg cap. Scalar K$->SGPR path is structurally right.
// R7 lesson: n_or gather removal cut FETCH 43->19MB but dur ~flat -> stall is
// the W1 s_load stream (512B/pair-iter vs ~320cy issue), depth-capped by the
// SGPR ceiling (112) and K$ thrash (21KB working set, bwd re-streams from row 0).
// R8: (1) kernarg diet via blob + derived pointers (free SGPRs -> deeper s_load
// pipelining); (2) backward j-loop REVERSED (62->0) so bwd first hits the
// stream tail still resident in scalar L1 (LRU-friendly re-use).
template<bool PRE>
__global__ void __launch_bounds__(320, 4)
energy_kernel_t(const float* __restrict__ orientation,
                const float* __restrict__ n_or,          // !PRE only
                const float* __restrict__ wsW,
                const float* __restrict__ wsD,           // = ws_R base
                const int*   __restrict__ ws_idx_fb,     // !PRE only
                const float* __restrict__ ws_ndn_fb,     // !PRE only
                float* __restrict__ outBase, const int Bn)
{
    __shared__ float sNr[320 * 9];     // 11.25 KB per-thread Nr stash
    __shared__ float p_s[320];
    __shared__ float red[320][12];
    __shared__ float G[16][12];

    // derived weight pointers (single SGPR base + immediate offsets)
    const float* W0T = wsW + OW0T;
    const float* b0  = wsW + OB0;
    const float* b1  = wsW + OB1;
    const float* W2  = wsW + OW2;
    const float* W1  = wsW + OW1;

    // derived data pointers
    const float* ws_R  = wsD;
    const float* ws_fc = wsD + (size_t)Bn * NSEL;
    const float* ws_F  = wsD + (size_t)Bn * (2 * NSEL);
    const float* ws_ndn = PRE ? (wsD + (size_t)Bn * (2 * NSEL + 1)) : ws_ndn_fb;
    const float* ws_nor = wsD + (size_t)Bn * (2 * NSEL + 1 + 3 * NSEL);

    const int t = threadIdx.x;
    const int bl = t / 20;      // local b (0..15)
    const int n  = t % 20;      // selected-neighbor slot
    const int b  = blockIdx.x * 16 + bl;
    const size_t o = (size_t)b * NSEL + n;

    // feat = [dr_o(3), dr_no(3), o_no(9)]; O/Nr/nd scoped so they die here.
    float feat[15];
    {
        const float nd0 = ws_ndn[o * 3 + 0];
        const float nd1 = ws_ndn[o * 3 + 1];
        const float nd2 = ws_ndn[o * 3 + 2];
        float O[9], Nr[9];
        const float* Op = orientation + (size_t)b * 9;
        #pragma unroll
        for (int i = 0; i < 9; ++i) O[i] = Op[i];
        if (PRE) {
            const float* Np = ws_nor + o * 9;
            #pragma unroll
            for (int i = 0; i < 9; ++i) Nr[i] = Np[i];
        } else {
            const int idx = ws_idx_fb[o];
            const float* Np = n_or + ((size_t)b * NB + idx) * 9;
            #pragma unroll
            for (int i = 0; i < 9; ++i) Nr[i] = Np[i];
        }
        // stash Nr for the epilogue (same thread reads it back: no barrier)
        #pragma unroll
        for (int q = 0; q < 9; ++q) sNr[t * 9 + q] = Nr[q];

        #pragma unroll
        for (int h = 0; h < 3; ++h)
            feat[h] = nd0 * O[h] + nd1 * O[3 + h] + nd2 * O[6 + h];
        #pragma unroll
        for (int h = 0; h < 3; ++h)
            feat[3 + h] = nd0 * Nr[h] + nd1 * Nr[3 + h] + nd2 * Nr[6 + h];
        #pragma unroll
        for (int l = 0; l < 3; ++l)
            #pragma unroll
            for (int m = 0; m < 3; ++m)
                feat[6 + l * 3 + m] = O[l] * Nr[m] + O[3 + l] * Nr[3 + m] + O[6 + l] * Nr[6 + m];
    }

    // ---------- forward (j, j+1 interleaved for 2x ILP on the serial chain) ----
    float acc[64];                      // z2 accumulators -> h2 -> dz2 (in place)
    #pragma unroll
    for (int i = 0; i < 64; ++i) acc[i] = b1[i];

    for (int j = 0; j < 64; j += 2) {
        const float* w0a = W0T + j * 16;
        const float* w0b = w0a + 16;
        float za = b0[j], zb = b0[j + 1];
        #pragma unroll
        for (int k = 0; k < 15; ++k) {
            za = fmaf(feat[k], w0a[k], za);
            zb = fmaf(feat[k], w0b[k], zb);
        }
        float ha = fast_tanh(za), hb = fast_tanh(zb);
        const float* w1a = W1 + j * 64;
        const float* w1b = w1a + 64;
        #pragma unroll
        for (int i = 0; i < 64; ++i)
            acc[i] = fmaf(hb, w1b[i], fmaf(ha, w1a[i], acc[i]));
    }

    // ---------- h2, z3 (4 partial sums) ----------
    float z30 = wsW[OB2], z31 = 0.f, z32 = 0.f, z33 = 0.f;
    #pragma unroll
    for (int i = 0; i < 64; i += 4) {
        acc[i]     = fast_tanh(acc[i]);
        acc[i + 1] = fast_tanh(acc[i + 1]);
        acc[i + 2] = fast_tanh(acc[i + 2]);
        acc[i + 3] = fast_tanh(acc[i + 3]);
        z30 = fmaf(acc[i],     W2[i],     z30);
        z31 = fmaf(acc[i + 1], W2[i + 1], z31);
        z32 = fmaf(acc[i + 2], W2[i + 2], z32);
        z33 = fmaf(acc[i + 3], W2[i + 3], z33);
    }
    const float enc = fast_tanh((z30 + z31) + (z32 + z33));
    float x;
    {
        const volatile float* Rv = ws_R + o;    // late load: don't hold R
        x = Rv[0] - (enc * enc + EPSF);
    }

    const float lx = __logf(x);
    float psum = 0.f, csum = 0.f;
    #pragma unroll
    for (int q = 0; q < 3; ++q) {
        float cq = wsW[OCQ + q];
        float tq = __expf(-cq * (wsW[OLG + q] + lx));   // (a*x)^(-c)
        psum += tq;
        csum = fmaf(cq, tq, csum);
    }
    const float dpdx = -__fdividef(csum, x);

    p_s[t] = psum;
    __syncthreads();
    {
        float S = 0.f;
        for (int m = 0; m < 20; ++m) S += p_s[bl * 20 + m];
        const volatile float* fcv = ws_fc + o;  // late load: don't hold fc
        outBase[(size_t)Bn * 6 + o] = S * fcv[0];       // out_energy
    }

    // ---------- backward ----------
    float dz3;
    {
        const volatile float* Fv = ws_F + b;    // late load: don't hold F
        dz3 = Fv[0] * dpdx * (-2.f * enc) * (1.f - enc * enc);
    }
    #pragma unroll
    for (int i = 0; i < 64; ++i) {
        float h2 = acc[i];
        acc[i] = dz3 * W2[i] * (1.f - h2 * h2);   // dz2
    }

    float dfeat[15];
    #pragma unroll
    for (int k = 0; k < 15; ++k) dfeat[k] = 0.f;

    // REVERSED: start at the stream tail (still K$-resident after the fwd pass)
    for (int j = 62; j >= 0; j -= 2) {
        const float* w1a = W1 + j * 64;
        const float* w1b = w1a + 64;
        float sa0 = 0.f, sa1 = 0.f, sb0 = 0.f, sb1 = 0.f;
        #pragma unroll
        for (int i = 0; i < 64; i += 2) {
            sa0 = fmaf(acc[i],     w1a[i],     sa0);
            sa1 = fmaf(acc[i + 1], w1a[i + 1], sa1);
            sb0 = fmaf(acc[i],     w1b[i],     sb0);
            sb1 = fmaf(acc[i + 1], w1b[i + 1], sb1);
        }
        float dha = sa0 + sa1, dhb = sb0 + sb1;
        const float* w0a = W0T + j * 16;
        const float* w0b = w0a + 16;
        float za = b0[j], zb = b0[j + 1];               // recompute h1 pair
        #pragma unroll
        for (int k = 0; k < 15; ++k) {
            za = fmaf(feat[k], w0a[k], za);
            zb = fmaf(feat[k], w0b[k], zb);
        }
        float ha = fast_tanh(za), hb = fast_tanh(zb);
        float dza = dha * (1.f - ha * ha);
        float dzb = dhb * (1.f - hb * hb);
        #pragma unroll
        for (int k = 0; k < 15; ++k)
            dfeat[k] = fmaf(dzb, w0b[k], fmaf(dza, w0a[k], dfeat[k]));
    }

    // ---- epilogue: O/nd reloaded (volatile, L2-cheap); Nr from LDS stash ----
    float O[9], Nr[9], nd0, nd1, nd2;
    {
        const volatile float* Ov = orientation + (size_t)b * 9;
        #pragma unroll
        for (int i = 0; i < 9; ++i) O[i] = Ov[i];
        volatile float* sv = sNr + t * 9;
        #pragma unroll
        for (int i = 0; i < 9; ++i) Nr[i] = sv[i];
        const volatile float* nv = ws_ndn + o * 3;
        nd0 = nv[0]; nd1 = nv[1]; nd2 = nv[2];
    }

    float gdr[3];
    #pragma unroll
    for (int k = 0; k < 3; ++k)
        gdr[k] = dfeat[0] * O[k * 3] + dfeat[1] * O[k * 3 + 1] + dfeat[2] * O[k * 3 + 2]
               + dfeat[3] * Nr[k * 3] + dfeat[4] * Nr[k * 3 + 1] + dfeat[5] * Nr[k * 3 + 2];

    float ndv[3] = {nd0, nd1, nd2};
    float gO[9];
    #pragma unroll
    for (int k = 0; k < 3; ++k)
        #pragma unroll
        for (int h = 0; h < 3; ++h)
            gO[k * 3 + h] = dfeat[h] * ndv[k];      // from dr_o
    #pragma unroll
    for (int h = 0; h < 3; ++h)
        #pragma unroll
        for (int l = 0; l < 3; ++l) {
            float s = 0.f;                          // from o_no
            #pragma unroll
            for (int m = 0; m < 3; ++m) s = fmaf(dfeat[6 + l * 3 + m], Nr[h * 3 + m], s);
            gO[h * 3 + l] += s;
        }

    #pragma unroll
    for (int q = 0; q < 3; ++q) red[t][q] = gdr[q];
    #pragma unroll
    for (int q = 0; q < 9; ++q) red[t][3 + q] = gO[q];
    __syncthreads();

    for (int i = t; i < 16 * 12; i += 320) {
        int bb = i / 12, q = i % 12;
        float s = 0.f;
        for (int m = 0; m < 20; ++m) s += red[bb * 20 + m][q];
        G[bb][q] = s;
    }
    __syncthreads();

    if (t < 16) {
        const int gb = blockIdx.x * 16 + t;
        float* out_force  = outBase;
        float* out_torque = outBase + (size_t)Bn * 3;
        out_force[gb * 3 + 0] = G[t][0];
        out_force[gb * 3 + 1] = G[t][1];
        out_force[gb * 3 + 2] = G[t][2];
        const float* Og = orientation + (size_t)gb * 9;
        float t0 = 0.f, t1 = 0.f, t2 = 0.f;
        #pragma unroll
        for (int jj = 0; jj < 3; ++jj) {
            float u0 = G[t][3 + 0 * 3 + jj], u1 = G[t][3 + 1 * 3 + jj], u2 = G[t][3 + 2 * 3 + jj];
            float v0 = Og[0 * 3 + jj], v1 = Og[1 * 3 + jj], v2 = Og[2 * 3 + jj];
            t0 += u1 * v2 - u2 * v1;
            t1 += u2 * v0 - u0 * v2;
            t2 += u0 * v1 - u1 * v0;
        }
        out_torque[gb * 3 + 0] = t0;
        out_torque[gb * 3 + 1] = t1;
        out_torque[gb * 3 + 2] = t2;
    }
}

extern "C" void kernel_launch(void* const* d_in, const int* in_sizes, int n_in,
                              void* d_out, int out_size, void* d_ws, size_t ws_size,
                              hipStream_t stream) {
    const float* dr            = (const float*)d_in[0];
    const float* orientation   = (const float*)d_in[1];
    const float* n_orientation = (const float*)d_in[2];
    const float* W0 = (const float*)d_in[3];
    const float* b0 = (const float*)d_in[4];
    const float* W1 = (const float*)d_in[5];
    const float* b1 = (const float*)d_in[6];
    const float* W2 = (const float*)d_in[7];
    const float* b2 = (const float*)d_in[8];
    const float* f1 = (const float*)d_in[9];
    const float* f2 = (const float*)d_in[10];

    const int B = in_sizes[0] / (NB * 3);   // 32768

    float* out = (float*)d_out;

    // PRE layout: R[B*20] fc[B*20] F[B] ndn[B*60] nor[B*180] wsW[5328]
    // FB  layout: R[B*20] fc[B*20] F[B] idx[B*20(int)] ndn[B*60] wsW[5328]
    float* ws_R  = (float*)d_ws;
    float* ws_fc = ws_R + (size_t)B * NSEL;
    float* ws_F  = ws_fc + (size_t)B * NSEL;

    const size_t needed_pre = sizeof(float) * ((size_t)B * 281 + WSWN);
    const bool pre = ws_size >= needed_pre;

    if (pre) {
        float* ws_ndn = ws_F + B;
        float* ws_nor = ws_ndn + (size_t)B * NSEL * 3;
        float* wsW    = ws_nor + (size_t)B * NSEL * 9;
        sel_kernel<<<B / 4, 256, 0, stream>>>(dr, n_orientation,
                                              W0, b0, W1, b1, W2, b2, f1, f2,
                                              ws_R, ws_fc, ws_F, nullptr,
                                              ws_ndn, ws_nor, wsW);
        energy_kernel_t<true><<<B / 16, 320, 0, stream>>>(
            orientation, n_orientation, wsW, ws_R, nullptr, nullptr, out, B);
    } else {
        int*   ws_idx = (int*)(ws_F + B);
        float* ws_ndn = (float*)(ws_idx + (size_t)B * NSEL);
        float* wsW    = ws_ndn + (size_t)B * NSEL * 3;
        sel_kernel<<<B / 4, 256, 0, stream>>>(dr, n_orientation,
                                              W0, b0, W1, b1, W2, b2, f1, f2,
                                              ws_R, ws_fc, ws_F, ws_idx,
                                              ws_ndn, nullptr, wsW);
        energy_kernel_t<false><<<B / 16, 320, 0, stream>>>(
            orientation, n_orientation, wsW, ws_R, ws_idx, ws_ndn, out, B);
    }
}